// Round 4
// baseline (304.322 us; speedup 1.0000x reference)
//
#include <hip/hip_runtime.h>
#include <math.h>

#define NH   8
#define HD   64
#define BS   4
#define SEQL 2048
#define DIMX 768
#define EMB  512
#define MROWS (BS*SEQL)

typedef __attribute__((ext_vector_type(4))) float          f32x4;
typedef __attribute__((ext_vector_type(8))) __bf16         bf16x8;
typedef __attribute__((ext_vector_type(8))) unsigned short u16x8;
typedef __attribute__((ext_vector_type(4))) unsigned short u16x4;

union BF8 { u16x8 u; bf16x8 b; };

__device__ __forceinline__ unsigned short f2bf(float x) {   // RNE
    unsigned int u = __float_as_uint(x);
    u += 0x7FFFu + ((u >> 16) & 1u);
    return (unsigned short)(u >> 16);
}

#if __has_builtin(__builtin_amdgcn_exp2f)
#define EXP2F(x) __builtin_amdgcn_exp2f(x)
#else
#define EXP2F(x) exp2f(x)
#endif

__device__ __forceinline__ bf16x8 ldb8(const unsigned short* p) {
    return *(const bf16x8*)p;
}

// ---------------------------------------------------------------------------
// Cast query/key/value fp32 -> bf16 (RNE), one dispatch, grid.y picks tensor.
// ---------------------------------------------------------------------------
__global__ __launch_bounds__(256)
void cast3(const float* __restrict__ q, const float* __restrict__ k,
           const float* __restrict__ v, unsigned short* __restrict__ out)
{
    const float* src = blockIdx.y == 0 ? q : (blockIdx.y == 1 ? k : v);
    unsigned short* dst = out + (size_t)blockIdx.y * (MROWS * DIMX);
    const int n4 = MROWS * DIMX / 4;
    for (int i = blockIdx.x * 256 + threadIdx.x; i < n4; i += gridDim.x * 256) {
        f32x4 x = ((const f32x4*)src)[i];
        u16x4 o;
        o[0] = f2bf(x[0]); o[1] = f2bf(x[1]); o[2] = f2bf(x[2]); o[3] = f2bf(x[3]);
        ((u16x4*)dst)[i] = o;
    }
}

// ---------------------------------------------------------------------------
// All 4 weight transposes in ONE dispatch: fp32 [R][C] -> bf16 [C][R].
// ---------------------------------------------------------------------------
__global__ __launch_bounds__(256)
void transpose_w4(const float* __restrict__ w0, const float* __restrict__ w1,
                  const float* __restrict__ w2, const float* __restrict__ w3,
                  unsigned short* __restrict__ o0, unsigned short* __restrict__ o1,
                  unsigned short* __restrict__ o2, unsigned short* __restrict__ o3)
{
    __shared__ float sm[32][33];
    const int which = blockIdx.y;
    const float* in; unsigned short* out; int R, C;
    if      (which == 0) { in = w0; out = o0; R = DIMX; C = EMB;  }
    else if (which == 1) { in = w1; out = o1; R = DIMX; C = EMB;  }
    else if (which == 2) { in = w2; out = o2; R = DIMX; C = EMB;  }
    else                 { in = w3; out = o3; R = EMB;  C = DIMX; }
    const int nbx = C / 32;
    const int rB = (blockIdx.x / nbx) * 32, cB = (blockIdx.x % nbx) * 32;
    const int row = threadIdx.x >> 3, c4 = (threadIdx.x & 7) * 4;
    f32x4 v = *(const f32x4*)&in[(size_t)(rB + row) * C + cB + c4];
    sm[row][c4 + 0] = v[0]; sm[row][c4 + 1] = v[1];
    sm[row][c4 + 2] = v[2]; sm[row][c4 + 3] = v[3];
    __syncthreads();
    u16x4 o;
    o[0] = f2bf(sm[c4 + 0][row]); o[1] = f2bf(sm[c4 + 1][row]);
    o[2] = f2bf(sm[c4 + 2][row]); o[3] = f2bf(sm[c4 + 3][row]);
    *(u16x4*)&out[(size_t)(cB + row) * R + rB + c4] = o;
}

// ---------------------------------------------------------------------------
// Shared GEMM core: 128x128 tile, BK=64, 256 threads (4 waves as 2x2),
// bf16 A[M,K] @ Bt[N,K]^T, LDS padded stride 72 (conflict-free b128).
// DIRECT:  acc[mt][nt] = mfma(x, w)  -> row=m, col=n   (V-transposed epilogue)
// !DIRECT: acc[nt][mt] = mfma(w, x)  -> row=n, col=m   (packed row-major out)
// ---------------------------------------------------------------------------
template<bool DIRECT>
__device__ __forceinline__ void gemm_core(
    const unsigned short* __restrict__ A, const unsigned short* __restrict__ Bt,
    int K, int mBase, int nBase,
    unsigned short* __restrict__ smA, unsigned short* __restrict__ smB,
    f32x4 (&acc)[4][4])
{
    const int tid = threadIdx.x;
    const int lane = tid & 63, w = tid >> 6;
    const int quad = lane >> 4, lanem = lane & 15;
    const int wm = w >> 1, wn = w & 1;
    const int srow = tid >> 3, c8 = (tid & 7) * 8;

    const f32x4 z4 = {0.f, 0.f, 0.f, 0.f};
    #pragma unroll
    for (int i = 0; i < 4; ++i)
        #pragma unroll
        for (int j = 0; j < 4; ++j) acc[i][j] = z4;

    for (int k0 = 0; k0 < K; k0 += 64) {
        u16x8 va[4], vb[4];
        #pragma unroll
        for (int p = 0; p < 4; ++p) {
            va[p] = *(const u16x8*)&A[(size_t)(mBase + srow + p * 32) * K + k0 + c8];
            vb[p] = *(const u16x8*)&Bt[(size_t)(nBase + srow + p * 32) * K + k0 + c8];
        }
        __syncthreads();   // guard previous iteration's frag reads
        #pragma unroll
        for (int p = 0; p < 4; ++p) {
            *(u16x8*)&smA[(srow + p * 32) * 72 + c8] = va[p];
            *(u16x8*)&smB[(srow + p * 32) * 72 + c8] = vb[p];
        }
        __syncthreads();
        #pragma unroll
        for (int kk = 0; kk < 64; kk += 32) {
            bf16x8 xa[4], wb[4];
            #pragma unroll
            for (int mt = 0; mt < 4; ++mt)
                xa[mt] = ldb8(&smA[(wm * 64 + mt * 16 + lanem) * 72 + kk + quad * 8]);
            #pragma unroll
            for (int nt = 0; nt < 4; ++nt)
                wb[nt] = ldb8(&smB[(wn * 64 + nt * 16 + lanem) * 72 + kk + quad * 8]);
            if constexpr (DIRECT) {
                #pragma unroll
                for (int mt = 0; mt < 4; ++mt)
                    #pragma unroll
                    for (int nt = 0; nt < 4; ++nt)
                        acc[mt][nt] = __builtin_amdgcn_mfma_f32_16x16x32_bf16(xa[mt], wb[nt], acc[mt][nt], 0, 0, 0);
            } else {
                #pragma unroll
                for (int nt = 0; nt < 4; ++nt)
                    #pragma unroll
                    for (int mt = 0; mt < 4; ++mt)
                        acc[nt][mt] = __builtin_amdgcn_mfma_f32_16x16x32_bf16(wb[nt], xa[mt], acc[nt][mt], 0, 0, 0);
            }
        }
    }
}

// ---------------------------------------------------------------------------
// Fused QKV projection: grid (4, 64, 3); z=0 Q (scaled), z=1 K, z=2 V->Vt.
// ---------------------------------------------------------------------------
__global__ __launch_bounds__(256)
void gemm_qkv(const unsigned short* __restrict__ Xc, const unsigned short* __restrict__ Wt,
              const float* __restrict__ bq, const float* __restrict__ bk,
              const float* __restrict__ bv,
              unsigned short* __restrict__ Qb, unsigned short* __restrict__ Kb,
              unsigned short* __restrict__ Vtb)
{
    __shared__ unsigned short smA[128 * 72];
    __shared__ unsigned short smB[128 * 72];
    const int z = blockIdx.z;
    const unsigned short* A  = Xc + (size_t)z * (MROWS * DIMX);
    const unsigned short* Bt = Wt + (size_t)z * (EMB * DIMX);
    const float* bias = z == 0 ? bq : (z == 1 ? bk : bv);
    const int mBase = blockIdx.y * 128, nBase = blockIdx.x * 128;

    const int tid = threadIdx.x;
    const int lane = tid & 63, w = tid >> 6;
    const int quad = lane >> 4, lanem = lane & 15;
    const int wm = w >> 1, wn = w & 1;

    f32x4 acc[4][4];
    if (z == 2) {
        gemm_core<true>(A, Bt, DIMX, mBase, nBase, smA, smB, acc);
        // V epilogue: write Vt[b][h][dh][s], 4 consecutive s per lane
        #pragma unroll
        for (int mt = 0; mt < 4; ++mt) {
            const int sg = mBase + wm * 64 + mt * 16 + quad * 4;
            const int b = sg >> 11, s = sg & 2047;
            #pragma unroll
            for (int nt = 0; nt < 4; ++nt) {
                const int de = nBase + wn * 64 + nt * 16 + lanem;
                const float bvv = bias[de];
                const int h = de >> 6, dh = de & 63;
                u16x4 ov;
                #pragma unroll
                for (int r = 0; r < 4; ++r) ov[r] = f2bf(acc[mt][nt][r] + bvv);
                *(u16x4*)&Vtb[((size_t)((b * NH + h) * HD + dh) << 11) + s] = ov;
            }
        }
    } else {
        gemm_core<false>(A, Bt, DIMX, mBase, nBase, smA, smB, acc);
        const float os = (z == 0) ? 0.18033688f : 1.0f;   // Q: (1/8)*log2(e) folded
        unsigned short* C = (z == 0) ? Qb : Kb;
        #pragma unroll
        for (int nt = 0; nt < 4; ++nt) {
            const int n0 = nBase + wn * 64 + nt * 16 + quad * 4;
            const f32x4 b4 = *(const f32x4*)&bias[n0];
            #pragma unroll
            for (int mt = 0; mt < 4; ++mt) {
                const int m = mBase + wm * 64 + mt * 16 + lanem;
                u16x4 ov;
                #pragma unroll
                for (int r = 0; r < 4; ++r) ov[r] = f2bf((acc[nt][mt][r] + b4[r]) * os);
                *(u16x4*)&C[(size_t)m * EMB + n0] = ov;
            }
        }
    }
}

// ---------------------------------------------------------------------------
// Output projection: X[8192,512]bf16 @ Wot[768,512]^T + bo -> fp32 out.
// ---------------------------------------------------------------------------
__global__ __launch_bounds__(256)
void gemm_out(const unsigned short* __restrict__ Xb, const unsigned short* __restrict__ Wot,
              const float* __restrict__ bo, float* __restrict__ out)
{
    __shared__ unsigned short smA[128 * 72];
    __shared__ unsigned short smB[128 * 72];
    const int mBase = blockIdx.y * 128, nBase = blockIdx.x * 128;
    const int tid = threadIdx.x;
    const int lane = tid & 63, w = tid >> 6;
    const int quad = lane >> 4, lanem = lane & 15;
    const int wm = w >> 1, wn = w & 1;

    f32x4 acc[4][4];
    gemm_core<false>(Xb, Wot, EMB, mBase, nBase, smA, smB, acc);
    #pragma unroll
    for (int nt = 0; nt < 4; ++nt) {
        const int n0 = nBase + wn * 64 + nt * 16 + quad * 4;
        const f32x4 b4 = *(const f32x4*)&bo[n0];
        #pragma unroll
        for (int mt = 0; mt < 4; ++mt) {
            const int m = mBase + wm * 64 + mt * 16 + lanem;
            f32x4 ov = acc[nt][mt] + b4;
            *(f32x4*)&out[(size_t)m * DIMX + n0] = ov;
        }
    }
}

// ---------------------------------------------------------------------------
// Fused flash attention, barrier-free. 256 thr = 4 waves, each wave owns 32 q
// rows end-to-end. K/V MFMA fragments load DIRECTLY from global (L1/L2-served,
// 64B segments) with next-iteration prefetch; LDS only for the per-wave P
// C-layout->A-layout round trip (no __syncthreads anywhere).
// S^T = mfma(K,Q); P = exp2(S^T) truncated to bf16; O^T = mfma(V^T,P);
// l via ones-row MFMA on the SAME truncated P (bias cancels in O/l).
// Grid: 512 blocks 1-D, XCD-swizzled so same-(b,h) blocks share an XCD L2.
// ---------------------------------------------------------------------------
__global__ __launch_bounds__(256)
void attn_mfma(const unsigned short* __restrict__ Qb, const unsigned short* __restrict__ Kb,
               const unsigned short* __restrict__ Vt, unsigned short* __restrict__ Xb)
{
    __shared__ unsigned short smP[4][32 * 72];
    const int id = blockIdx.x;
    const int bh = (id & 7) | (((id >> 3) & 3) << 3);   // id%8 = bh%8 -> same XCD
    const int qb = id >> 5;
    const int b = bh >> 3, h = bh & 7;

    const int tid = threadIdx.x;
    const int w = tid >> 6, lane = tid & 63;
    const int quad = lane >> 4, lanem = lane & 15;

    // Q fragments (already scaled by (1/8)*log2(e) in projection)
    bf16x8 aq[2][2];
    #pragma unroll
    for (int rg = 0; rg < 2; ++rg) {
        const size_t qrow = (size_t)(b * SEQL + qb * 128 + w * 32 + rg * 16 + lanem) * EMB + h * HD;
        aq[rg][0] = ldb8(&Qb[qrow + quad * 8]);
        aq[rg][1] = ldb8(&Qb[qrow + 32 + quad * 8]);
    }

    const f32x4 z4 = {0.f, 0.f, 0.f, 0.f};
    f32x4 o[4][2];            // O^T accum [dt][rg]
    f32x4 ls[2] = {z4, z4};   // row-sum accum (ones-row MFMA)
    #pragma unroll
    for (int dt = 0; dt < 4; ++dt)
        #pragma unroll
        for (int rg = 0; rg < 2; ++rg) o[dt][rg] = z4;

    BF8 ones;
    #pragma unroll
    for (int i = 0; i < 8; ++i) ones.u[i] = 0x3F80;   // bf16 1.0

    const unsigned short* Kbase = Kb + (size_t)b * SEQL * EMB + h * HD;
    const unsigned short* Vbase = Vt + (size_t)bh * HD * SEQL;
    unsigned short* pW = &smP[w][0];

    bf16x8 kf[4][2], vf[4][2];
    #pragma unroll
    for (int nt = 0; nt < 4; ++nt)
        #pragma unroll
        for (int hf = 0; hf < 2; ++hf) {
            kf[nt][hf] = ldb8(&Kbase[(size_t)(nt * 16 + lanem) * EMB + hf * 32 + quad * 8]);
            vf[nt][hf] = ldb8(&Vbase[(size_t)(nt * 16 + lanem) * SEQL + hf * 32 + quad * 8]);
        }

    for (int k0 = 0; k0 < SEQL; k0 += 64) {
        // prefetch next K/V tile fragments (redundant tile-0 reload on last iter)
        const int kn = (k0 + 64 < SEQL) ? k0 + 64 : 0;
        bf16x8 kfn[4][2], vfn[4][2];
        #pragma unroll
        for (int nt = 0; nt < 4; ++nt)
            #pragma unroll
            for (int hf = 0; hf < 2; ++hf) {
                kfn[nt][hf] = ldb8(&Kbase[(size_t)(kn + nt * 16 + lanem) * EMB + hf * 32 + quad * 8]);
                vfn[nt][hf] = ldb8(&Vbase[(size_t)(nt * 16 + lanem) * SEQL + kn + hf * 32 + quad * 8]);
            }

        // ---- S^T, exp2, truncated-pack P to LDS ----
        #pragma unroll
        for (int nt = 0; nt < 4; ++nt) {
            #pragma unroll
            for (int rg = 0; rg < 2; ++rg) {
                f32x4 s = __builtin_amdgcn_mfma_f32_16x16x32_bf16(kf[nt][0], aq[rg][0], z4, 0, 0, 0);
                s = __builtin_amdgcn_mfma_f32_16x16x32_bf16(kf[nt][1], aq[rg][1], s, 0, 0, 0);
                u16x4 pk;
                #pragma unroll
                for (int r = 0; r < 4; ++r)
                    pk[r] = (unsigned short)(__float_as_uint(EXP2F(s[r])) >> 16);
                *(u16x4*)&pW[(rg * 16 + lanem) * 72 + nt * 16 + quad * 4] = pk;
            }
        }
        // ---- P back as A-operand fragments (same wave; no barrier) ----
        bf16x8 pb[2][2];
        #pragma unroll
        for (int rg = 0; rg < 2; ++rg) {
            pb[rg][0] = ldb8(&pW[(rg * 16 + lanem) * 72 + quad * 8]);
            pb[rg][1] = ldb8(&pW[(rg * 16 + lanem) * 72 + 32 + quad * 8]);
        }
        // ---- O^T += V^T @ P^T ; l += ones @ P^T ----
        #pragma unroll
        for (int dt = 0; dt < 4; ++dt)
            #pragma unroll
            for (int rg = 0; rg < 2; ++rg) {
                o[dt][rg] = __builtin_amdgcn_mfma_f32_16x16x32_bf16(vf[dt][0], pb[rg][0], o[dt][rg], 0, 0, 0);
                o[dt][rg] = __builtin_amdgcn_mfma_f32_16x16x32_bf16(vf[dt][1], pb[rg][1], o[dt][rg], 0, 0, 0);
            }
        #pragma unroll
        for (int rg = 0; rg < 2; ++rg) {
            ls[rg] = __builtin_amdgcn_mfma_f32_16x16x32_bf16(ones.b, pb[rg][0], ls[rg], 0, 0, 0);
            ls[rg] = __builtin_amdgcn_mfma_f32_16x16x32_bf16(ones.b, pb[rg][1], ls[rg], 0, 0, 0);
        }
        #pragma unroll
        for (int nt = 0; nt < 4; ++nt)
            #pragma unroll
            for (int hf = 0; hf < 2; ++hf) { kf[nt][hf] = kfn[nt][hf]; vf[nt][hf] = vfn[nt][hf]; }
    }

    // epilogue: O^T row=d, col=q=lanem -> packed 8B stores along d
    #pragma unroll
    for (int rg = 0; rg < 2; ++rg) {
        const float rinv = 1.f / ls[rg][0];
        const size_t orow = (size_t)(b * SEQL + qb * 128 + w * 32 + rg * 16 + lanem) * EMB + h * HD;
        #pragma unroll
        for (int dt = 0; dt < 4; ++dt) {
            u16x4 ov;
            #pragma unroll
            for (int r = 0; r < 4; ++r) ov[r] = f2bf(o[dt][rg][r] * rinv);
            *(u16x4*)&Xb[orow + dt * 16 + quad * 4] = ov;
        }
    }
}

// ---------------------------------------------------------------------------
extern "C" void kernel_launch(void* const* d_in, const int* in_sizes, int n_in,
                              void* d_out, int out_size, void* d_ws, size_t ws_size,
                              hipStream_t stream) {
    (void)in_sizes; (void)n_in; (void)out_size; (void)ws_size;
    const float* query = (const float*)d_in[0];
    const float* key   = (const float*)d_in[1];
    const float* value = (const float*)d_in[2];
    const float* wq = (const float*)d_in[3];
    const float* bq = (const float*)d_in[4];
    const float* wk = (const float*)d_in[5];
    const float* bk = (const float*)d_in[6];
    const float* wv = (const float*)d_in[7];
    const float* bv = (const float*)d_in[8];
    const float* wo = (const float*)d_in[9];
    const float* bo = (const float*)d_in[10];
    float* out = (float*)d_out;

    char* ws = (char*)d_ws;
    unsigned short* castb = (unsigned short*)(ws);              // 37,748,736 B (3 tensors)
    unsigned short* Xbuf  = (unsigned short*)(ws);              // aliases castb (dead after qkv gemm)
    unsigned short* Wt    = (unsigned short*)(ws + 37748736);   //  2,359,296 B (wq,wk,wv ^T)
    unsigned short* Wot   = (unsigned short*)(ws + 40108032);   //    786,432 B
    unsigned short* Qbuf  = (unsigned short*)(ws + 40894464);   //  8,388,608 B
    unsigned short* Kbuf  = (unsigned short*)(ws + 49283072);   //  8,388,608 B
    unsigned short* Vtb   = (unsigned short*)(ws + 57671680);   //  8,388,608 B -> ends 66,060,288

    const dim3 blk(256);

    transpose_w4<<<dim3(384, 4), blk, 0, stream>>>(wq, wk, wv, wo,
        Wt, Wt + (size_t)EMB * DIMX, Wt + 2 * (size_t)EMB * DIMX, Wot);
    cast3<<<dim3(1024, 3), blk, 0, stream>>>(query, key, value, castb);

    gemm_qkv<<<dim3(EMB / 128, MROWS / 128, 3), blk, 0, stream>>>(
        castb, Wt, bq, bk, bv, Qbuf, Kbuf, Vtb);

    attn_mfma<<<dim3(512), blk, 0, stream>>>(Qbuf, Kbuf, Vtb, Xbuf);

    gemm_out<<<dim3(DIMX / 128, MROWS / 128), blk, 0, stream>>>(Xbuf, Wot, bo, out);
}

// Round 5
// 247.590 us; speedup vs baseline: 1.2291x; 1.2291x over previous
//
#include <hip/hip_runtime.h>
#include <math.h>

#define NH   8
#define HD   64
#define BS   4
#define SEQL 2048
#define DIMX 768
#define EMB  512
#define MROWS (BS*SEQL)
#define NSPLIT 2
#define KSPAN (SEQL/NSPLIT)

typedef __attribute__((ext_vector_type(4))) float          f32x4;
typedef __attribute__((ext_vector_type(8))) __bf16         bf16x8;
typedef __attribute__((ext_vector_type(8))) unsigned short u16x8;
typedef __attribute__((ext_vector_type(4))) unsigned short u16x4;

union BF8 { u16x8 u; bf16x8 b; };

__device__ __forceinline__ unsigned short f2bf(float x) {   // RNE
    unsigned int u = __float_as_uint(x);
    u += 0x7FFFu + ((u >> 16) & 1u);
    return (unsigned short)(u >> 16);
}

#if __has_builtin(__builtin_amdgcn_exp2f)
#define EXP2F(x) __builtin_amdgcn_exp2f(x)
#else
#define EXP2F(x) exp2f(x)
#endif

__device__ __forceinline__ bf16x8 ldb8(const unsigned short* p) {
    return *(const bf16x8*)p;
}

// ---------------------------------------------------------------------------
// Cast query/key/value fp32 -> bf16 (RNE), one dispatch, grid.y picks tensor.
// ---------------------------------------------------------------------------
__global__ __launch_bounds__(256)
void cast3(const float* __restrict__ q, const float* __restrict__ k,
           const float* __restrict__ v, unsigned short* __restrict__ out)
{
    const float* src = blockIdx.y == 0 ? q : (blockIdx.y == 1 ? k : v);
    unsigned short* dst = out + (size_t)blockIdx.y * (MROWS * DIMX);
    const int n4 = MROWS * DIMX / 4;
    for (int i = blockIdx.x * 256 + threadIdx.x; i < n4; i += gridDim.x * 256) {
        f32x4 x = ((const f32x4*)src)[i];
        u16x4 o;
        o[0] = f2bf(x[0]); o[1] = f2bf(x[1]); o[2] = f2bf(x[2]); o[3] = f2bf(x[3]);
        ((u16x4*)dst)[i] = o;
    }
}

// ---------------------------------------------------------------------------
// All 4 weight transposes in ONE dispatch: fp32 [R][C] -> bf16 [C][R].
// ---------------------------------------------------------------------------
__global__ __launch_bounds__(256)
void transpose_w4(const float* __restrict__ w0, const float* __restrict__ w1,
                  const float* __restrict__ w2, const float* __restrict__ w3,
                  unsigned short* __restrict__ o0, unsigned short* __restrict__ o1,
                  unsigned short* __restrict__ o2, unsigned short* __restrict__ o3)
{
    __shared__ float sm[32][33];
    const int which = blockIdx.y;
    const float* in; unsigned short* out; int R, C;
    if      (which == 0) { in = w0; out = o0; R = DIMX; C = EMB;  }
    else if (which == 1) { in = w1; out = o1; R = DIMX; C = EMB;  }
    else if (which == 2) { in = w2; out = o2; R = DIMX; C = EMB;  }
    else                 { in = w3; out = o3; R = EMB;  C = DIMX; }
    const int nbx = C / 32;
    const int rB = (blockIdx.x / nbx) * 32, cB = (blockIdx.x % nbx) * 32;
    const int row = threadIdx.x >> 3, c4 = (threadIdx.x & 7) * 4;
    f32x4 v = *(const f32x4*)&in[(size_t)(rB + row) * C + cB + c4];
    sm[row][c4 + 0] = v[0]; sm[row][c4 + 1] = v[1];
    sm[row][c4 + 2] = v[2]; sm[row][c4 + 3] = v[3];
    __syncthreads();
    u16x4 o;
    o[0] = f2bf(sm[c4 + 0][row]); o[1] = f2bf(sm[c4 + 1][row]);
    o[2] = f2bf(sm[c4 + 2][row]); o[3] = f2bf(sm[c4 + 3][row]);
    *(u16x4*)&out[(size_t)(cB + row) * R + rB + c4] = o;
}

// ---------------------------------------------------------------------------
// Shared GEMM core: 128x128 tile, BK=64, 256 threads (4 waves as 2x2),
// bf16 A[M,K] @ Bt[N,K]^T, LDS padded stride 72 (conflict-free b128).
// DIRECT:  acc[mt][nt] = mfma(x, w)  -> row=m, col=n   (V-transposed epilogue)
// !DIRECT: acc[nt][mt] = mfma(w, x)  -> row=n, col=m   (packed row-major out)
// ---------------------------------------------------------------------------
template<bool DIRECT>
__device__ __forceinline__ void gemm_core(
    const unsigned short* __restrict__ A, const unsigned short* __restrict__ Bt,
    int K, int mBase, int nBase,
    unsigned short* __restrict__ smA, unsigned short* __restrict__ smB,
    f32x4 (&acc)[4][4])
{
    const int tid = threadIdx.x;
    const int lane = tid & 63, w = tid >> 6;
    const int quad = lane >> 4, lanem = lane & 15;
    const int wm = w >> 1, wn = w & 1;
    const int srow = tid >> 3, c8 = (tid & 7) * 8;

    const f32x4 z4 = {0.f, 0.f, 0.f, 0.f};
    #pragma unroll
    for (int i = 0; i < 4; ++i)
        #pragma unroll
        for (int j = 0; j < 4; ++j) acc[i][j] = z4;

    for (int k0 = 0; k0 < K; k0 += 64) {
        u16x8 va[4], vb[4];
        #pragma unroll
        for (int p = 0; p < 4; ++p) {
            va[p] = *(const u16x8*)&A[(size_t)(mBase + srow + p * 32) * K + k0 + c8];
            vb[p] = *(const u16x8*)&Bt[(size_t)(nBase + srow + p * 32) * K + k0 + c8];
        }
        __syncthreads();   // guard previous iteration's frag reads
        #pragma unroll
        for (int p = 0; p < 4; ++p) {
            *(u16x8*)&smA[(srow + p * 32) * 72 + c8] = va[p];
            *(u16x8*)&smB[(srow + p * 32) * 72 + c8] = vb[p];
        }
        __syncthreads();
        #pragma unroll
        for (int kk = 0; kk < 64; kk += 32) {
            bf16x8 xa[4], wb[4];
            #pragma unroll
            for (int mt = 0; mt < 4; ++mt)
                xa[mt] = ldb8(&smA[(wm * 64 + mt * 16 + lanem) * 72 + kk + quad * 8]);
            #pragma unroll
            for (int nt = 0; nt < 4; ++nt)
                wb[nt] = ldb8(&smB[(wn * 64 + nt * 16 + lanem) * 72 + kk + quad * 8]);
            if constexpr (DIRECT) {
                #pragma unroll
                for (int mt = 0; mt < 4; ++mt)
                    #pragma unroll
                    for (int nt = 0; nt < 4; ++nt)
                        acc[mt][nt] = __builtin_amdgcn_mfma_f32_16x16x32_bf16(xa[mt], wb[nt], acc[mt][nt], 0, 0, 0);
            } else {
                #pragma unroll
                for (int nt = 0; nt < 4; ++nt)
                    #pragma unroll
                    for (int mt = 0; mt < 4; ++mt)
                        acc[nt][mt] = __builtin_amdgcn_mfma_f32_16x16x32_bf16(wb[nt], xa[mt], acc[nt][mt], 0, 0, 0);
            }
        }
    }
}

// ---------------------------------------------------------------------------
// Fused QKV projection: grid (4, 64, 3); z=0 Q (scaled), z=1 K, z=2 V->Vt.
// ---------------------------------------------------------------------------
__global__ __launch_bounds__(256)
void gemm_qkv(const unsigned short* __restrict__ Xc, const unsigned short* __restrict__ Wt,
              const float* __restrict__ bq, const float* __restrict__ bk,
              const float* __restrict__ bv,
              unsigned short* __restrict__ Qb, unsigned short* __restrict__ Kb,
              unsigned short* __restrict__ Vtb)
{
    __shared__ unsigned short smA[128 * 72];
    __shared__ unsigned short smB[128 * 72];
    const int z = blockIdx.z;
    const unsigned short* A  = Xc + (size_t)z * (MROWS * DIMX);
    const unsigned short* Bt = Wt + (size_t)z * (EMB * DIMX);
    const float* bias = z == 0 ? bq : (z == 1 ? bk : bv);
    const int mBase = blockIdx.y * 128, nBase = blockIdx.x * 128;

    const int tid = threadIdx.x;
    const int lane = tid & 63, w = tid >> 6;
    const int quad = lane >> 4, lanem = lane & 15;
    const int wm = w >> 1, wn = w & 1;

    f32x4 acc[4][4];
    if (z == 2) {
        gemm_core<true>(A, Bt, DIMX, mBase, nBase, smA, smB, acc);
        // V epilogue: write Vt[b][h][dh][s], 4 consecutive s per lane
        #pragma unroll
        for (int mt = 0; mt < 4; ++mt) {
            const int sg = mBase + wm * 64 + mt * 16 + quad * 4;
            const int b = sg >> 11, s = sg & 2047;
            #pragma unroll
            for (int nt = 0; nt < 4; ++nt) {
                const int de = nBase + wn * 64 + nt * 16 + lanem;
                const float bvv = bias[de];
                const int h = de >> 6, dh = de & 63;
                u16x4 ov;
                #pragma unroll
                for (int r = 0; r < 4; ++r) ov[r] = f2bf(acc[mt][nt][r] + bvv);
                *(u16x4*)&Vtb[((size_t)((b * NH + h) * HD + dh) << 11) + s] = ov;
            }
        }
    } else {
        gemm_core<false>(A, Bt, DIMX, mBase, nBase, smA, smB, acc);
        const float os = (z == 0) ? 0.18033688f : 1.0f;   // Q: (1/8)*log2(e) folded
        unsigned short* C = (z == 0) ? Qb : Kb;
        #pragma unroll
        for (int nt = 0; nt < 4; ++nt) {
            const int n0 = nBase + wn * 64 + nt * 16 + quad * 4;
            const f32x4 b4 = *(const f32x4*)&bias[n0];
            #pragma unroll
            for (int mt = 0; mt < 4; ++mt) {
                const int m = mBase + wm * 64 + mt * 16 + lanem;
                u16x4 ov;
                #pragma unroll
                for (int r = 0; r < 4; ++r) ov[r] = f2bf((acc[nt][mt][r] + b4[r]) * os);
                *(u16x4*)&C[(size_t)m * EMB + n0] = ov;
            }
        }
    }
}

// ---------------------------------------------------------------------------
// Output projection: X[8192,512]bf16 @ Wot[768,512]^T + bo -> fp32 out.
// ---------------------------------------------------------------------------
__global__ __launch_bounds__(256)
void gemm_out(const unsigned short* __restrict__ Xb, const unsigned short* __restrict__ Wot,
              const float* __restrict__ bo, float* __restrict__ out)
{
    __shared__ unsigned short smA[128 * 72];
    __shared__ unsigned short smB[128 * 72];
    const int mBase = blockIdx.y * 128, nBase = blockIdx.x * 128;
    const int tid = threadIdx.x;
    const int lane = tid & 63, w = tid >> 6;
    const int quad = lane >> 4, lanem = lane & 15;
    const int wm = w >> 1, wn = w & 1;

    f32x4 acc[4][4];
    gemm_core<false>(Xb, Wot, EMB, mBase, nBase, smA, smB, acc);
    #pragma unroll
    for (int nt = 0; nt < 4; ++nt) {
        const int n0 = nBase + wn * 64 + nt * 16 + quad * 4;
        const f32x4 b4 = *(const f32x4*)&bo[n0];
        #pragma unroll
        for (int mt = 0; mt < 4; ++mt) {
            const int m = mBase + wm * 64 + mt * 16 + lanem;
            f32x4 ov = acc[nt][mt] + b4;
            *(f32x4*)&out[(size_t)m * DIMX + n0] = ov;
        }
    }
}

// ---------------------------------------------------------------------------
// Fused flash attention, LDS-staged, SPLIT-K over the key dimension.
// Grid 1024 blocks: (bh 32) x (qb 16) x (split 2), XCD-swizzled so blocks on
// one XCD share (b,h). Block = 256 thr = 4 waves; wave owns 32 q rows.
// Each block processes KSPAN=1024 keys and writes ADDITIVE partials
// (no-max softmax => partials combine by plain summation):
//   Opart[split][bh][q][d] fp32, lpart[split][bh][q] fp32.
// S^T = mfma(K,Q); P = exp2 (log2e/8 folded into Q), truncated bf16 pack;
// O^T = mfma(V^T,P); l via ones-row MFMA on the same truncated P.
// LDS tiles padded stride 72 (conflict-free b128).
// ---------------------------------------------------------------------------
__global__ __launch_bounds__(256)
void attn_mfma(const unsigned short* __restrict__ Qb, const unsigned short* __restrict__ Kb,
               const unsigned short* __restrict__ Vt,
               float* __restrict__ Opart, float* __restrict__ lpart)
{
    __shared__ unsigned short smK[64 * 72];
    __shared__ unsigned short smV[64 * 72];          // V^T tile: [d][k]
    __shared__ unsigned short smP[4][32 * 72];       // per-wave P tile: [q][k]
    const int id = blockIdx.x;
    const int bh = ((id & 7) << 2) | ((id >> 3) & 3);   // id%8 fixed -> same 4 bh per XCD
    const int rest = id >> 5;
    const int qb = rest & 15, sp = rest >> 4;
    const int b = bh >> 3, h = bh & 7;

    const int tid = threadIdx.x;
    const int w = tid >> 6, lane = tid & 63;
    const int quad = lane >> 4, lanem = lane & 15;

    // Q fragments (already scaled by (1/8)*log2(e) in projection)
    bf16x8 aq[2][2];
    #pragma unroll
    for (int rg = 0; rg < 2; ++rg) {
        const size_t qrow = (size_t)(b * SEQL + qb * 128 + w * 32 + rg * 16 + lanem) * EMB + h * HD;
        aq[rg][0] = ldb8(&Qb[qrow + quad * 8]);
        aq[rg][1] = ldb8(&Qb[qrow + 32 + quad * 8]);
    }

    const f32x4 z4 = {0.f, 0.f, 0.f, 0.f};
    f32x4 o[4][2];            // O^T accum [dt][rg]
    f32x4 ls[2] = {z4, z4};   // row-sum accum (ones-row MFMA)
    #pragma unroll
    for (int dt = 0; dt < 4; ++dt)
        #pragma unroll
        for (int rg = 0; rg < 2; ++rg) o[dt][rg] = z4;

    BF8 ones;
    #pragma unroll
    for (int i = 0; i < 8; ++i) ones.u[i] = 0x3F80;   // bf16 1.0

    const unsigned short* Kbase = Kb + (size_t)b * SEQL * EMB + h * HD;
    const unsigned short* Vbase = Vt + (size_t)bh * HD * SEQL;
    unsigned short* pW = &smP[w][0];
    const int srow = tid >> 3, c8 = (tid & 7) * 8;   // staging map (2 rows apart per p)

    for (int t = 0; t < KSPAN / 64; ++t) {
        const int k0 = sp * KSPAN + t * 64;
        u16x8 kv[2], vv[2];
        #pragma unroll
        for (int p = 0; p < 2; ++p) {
            kv[p] = *(const u16x8*)&Kbase[(size_t)(k0 + srow + p * 32) * EMB + c8];
            vv[p] = *(const u16x8*)&Vbase[(size_t)(srow + p * 32) * SEQL + k0 + c8];
        }
        __syncthreads();  // guard previous iteration's frag reads
        #pragma unroll
        for (int p = 0; p < 2; ++p) {
            *(u16x8*)&smK[(srow + p * 32) * 72 + c8] = kv[p];
            *(u16x8*)&smV[(srow + p * 32) * 72 + c8] = vv[p];
        }
        __syncthreads();

        // ---- S^T, exp2, truncated-pack P to LDS ----
        #pragma unroll
        for (int nt = 0; nt < 4; ++nt) {
            bf16x8 bk0 = ldb8(&smK[(nt * 16 + lanem) * 72 + quad * 8]);
            bf16x8 bk1 = ldb8(&smK[(nt * 16 + lanem) * 72 + 32 + quad * 8]);
            #pragma unroll
            for (int rg = 0; rg < 2; ++rg) {
                f32x4 s = __builtin_amdgcn_mfma_f32_16x16x32_bf16(bk0, aq[rg][0], z4, 0, 0, 0);
                s = __builtin_amdgcn_mfma_f32_16x16x32_bf16(bk1, aq[rg][1], s, 0, 0, 0);
                u16x4 pk;
                #pragma unroll
                for (int r = 0; r < 4; ++r)
                    pk[r] = (unsigned short)(__float_as_uint(EXP2F(s[r])) >> 16);
                *(u16x4*)&pW[(rg * 16 + lanem) * 72 + nt * 16 + quad * 4] = pk;
            }
        }
        // ---- P back as B-operand fragments (same wave; no barrier) ----
        bf16x8 pb[2][2];
        #pragma unroll
        for (int rg = 0; rg < 2; ++rg) {
            pb[rg][0] = ldb8(&pW[(rg * 16 + lanem) * 72 + quad * 8]);
            pb[rg][1] = ldb8(&pW[(rg * 16 + lanem) * 72 + 32 + quad * 8]);
        }
        // ---- O^T += V^T @ P^T ; l += ones @ P^T ----
        #pragma unroll
        for (int dt = 0; dt < 4; ++dt) {
            bf16x8 av0 = ldb8(&smV[(dt * 16 + lanem) * 72 + quad * 8]);
            bf16x8 av1 = ldb8(&smV[(dt * 16 + lanem) * 72 + 32 + quad * 8]);
            #pragma unroll
            for (int rg = 0; rg < 2; ++rg) {
                o[dt][rg] = __builtin_amdgcn_mfma_f32_16x16x32_bf16(av0, pb[rg][0], o[dt][rg], 0, 0, 0);
                o[dt][rg] = __builtin_amdgcn_mfma_f32_16x16x32_bf16(av1, pb[rg][1], o[dt][rg], 0, 0, 0);
            }
        }
        #pragma unroll
        for (int rg = 0; rg < 2; ++rg) {
            ls[rg] = __builtin_amdgcn_mfma_f32_16x16x32_bf16(ones.b, pb[rg][0], ls[rg], 0, 0, 0);
            ls[rg] = __builtin_amdgcn_mfma_f32_16x16x32_bf16(ones.b, pb[rg][1], ls[rg], 0, 0, 0);
        }
    }

    // epilogue: additive fp32 partials. O^T: col=q=lanem, row=d=dt*16+quad*4+r.
    #pragma unroll
    for (int rg = 0; rg < 2; ++rg) {
        const int qloc = qb * 128 + w * 32 + rg * 16 + lanem;
        float* orow = Opart + ((size_t)sp * 32 * SEQL + (size_t)bh * SEQL + qloc) * HD;
        #pragma unroll
        for (int dt = 0; dt < 4; ++dt)
            *(f32x4*)&orow[dt * 16 + quad * 4] = o[dt][rg];
        if (quad == 0)
            lpart[(size_t)sp * 32 * SEQL + (size_t)bh * SEQL + qloc] = ls[rg][0];
    }
}

// ---------------------------------------------------------------------------
// Combine split partials + normalize + cast: Xb[b*S+q][h*64+d] bf16.
// ---------------------------------------------------------------------------
__global__ __launch_bounds__(256)
void attn_reduce(const float* __restrict__ Opart, const float* __restrict__ lpart,
                 unsigned short* __restrict__ Xb)
{
    const int lin = blockIdx.x * 256 + threadIdx.x;   // 1,048,576 threads
    const int d4 = (lin & 15) << 2;
    const int q = (lin >> 4) & 2047;
    const int bh = lin >> 15;
    const int b = bh >> 3, h = bh & 7;
    const size_t base = ((size_t)bh * SEQL + q) * HD + d4;
    const size_t soff = (size_t)32 * SEQL * HD;
    f32x4 o0 = *(const f32x4*)&Opart[base];
    f32x4 o1 = *(const f32x4*)&Opart[base + soff];
    const float l0 = lpart[(size_t)bh * SEQL + q];
    const float l1 = lpart[(size_t)32 * SEQL + (size_t)bh * SEQL + q];
    const float rl = 1.f / (l0 + l1);
    u16x4 ov;
    #pragma unroll
    for (int r = 0; r < 4; ++r) ov[r] = f2bf((o0[r] + o1[r]) * rl);
    *(u16x4*)&Xb[((size_t)(b * SEQL + q)) * EMB + h * HD + d4] = ov;
}

// ---------------------------------------------------------------------------
extern "C" void kernel_launch(void* const* d_in, const int* in_sizes, int n_in,
                              void* d_out, int out_size, void* d_ws, size_t ws_size,
                              hipStream_t stream) {
    (void)in_sizes; (void)n_in; (void)out_size; (void)ws_size;
    const float* query = (const float*)d_in[0];
    const float* key   = (const float*)d_in[1];
    const float* value = (const float*)d_in[2];
    const float* wq = (const float*)d_in[3];
    const float* bq = (const float*)d_in[4];
    const float* wk = (const float*)d_in[5];
    const float* bk = (const float*)d_in[6];
    const float* wv = (const float*)d_in[7];
    const float* bv = (const float*)d_in[8];
    const float* wo = (const float*)d_in[9];
    const float* bo = (const float*)d_in[10];
    float* out = (float*)d_out;

    char* ws = (char*)d_ws;
    // Region [0, 37.75 MB): castb while projecting; Opart+lpart during attn
    // (castb dead after gemm_qkv).
    unsigned short* castb = (unsigned short*)(ws);              // 37,748,736 B
    float*          Opart = (float*)(ws);                       // 33,554,432 B
    float*          lpart = (float*)(ws + 33554432);            //    524,288 B
    unsigned short* Wt    = (unsigned short*)(ws + 37748736);   //  2,359,296 B
    unsigned short* Wot   = (unsigned short*)(ws + 40108032);   //    786,432 B
    unsigned short* Qbuf  = (unsigned short*)(ws + 40894464);   //  8,388,608 B
    unsigned short* Xbuf  = Qbuf;                               // aliases Qbuf (dead after attn)
    unsigned short* Kbuf  = (unsigned short*)(ws + 49283072);   //  8,388,608 B
    unsigned short* Vtb   = (unsigned short*)(ws + 57671680);   //  8,388,608 B -> ends 66,060,288

    const dim3 blk(256);

    transpose_w4<<<dim3(384, 4), blk, 0, stream>>>(wq, wk, wv, wo,
        Wt, Wt + (size_t)EMB * DIMX, Wt + 2 * (size_t)EMB * DIMX, Wot);
    cast3<<<dim3(1024, 3), blk, 0, stream>>>(query, key, value, castb);

    gemm_qkv<<<dim3(EMB / 128, MROWS / 128, 3), blk, 0, stream>>>(
        castb, Wt, bq, bk, bv, Qbuf, Kbuf, Vtb);

    attn_mfma<<<dim3(32 * 16 * NSPLIT), blk, 0, stream>>>(Qbuf, Kbuf, Vtb, Opart, lpart);
    attn_reduce<<<dim3(4096), blk, 0, stream>>>(Opart, lpart, Xbuf);

    gemm_out<<<dim3(DIMX / 128, MROWS / 128), blk, 0, stream>>>(Xbuf, Wot, bo, out);
}